// Round 3
// baseline (191.741 us; speedup 1.0000x reference)
//
#include <hip/hip_runtime.h>

#define NIMG 16
#define H 512
#define W 512

// Streaming tile: 64 output rows x 128 output cols per block.
// Grid = 16 img * 8 bands * 4 col-quarters = 512 blocks (2/CU), 256 threads.
#define DYW 148   // dY staging row width (144 used: cols C0-8 .. C0+135)
#define UVW 84    // dUV staging width (80 used: pooled cols C0/2-8 .. C0/2+71)
#define HBYW 132  // luma hbox ring row width (128 used)
#define HBCW 68   // chroma hbox ring width (64 used)
#define NHBY 20   // luma ring rows (live range 20: reads back 18, concurrent writes +2)
#define NHBC 18   // chroma ring rows (live range 17)

static __device__ __forceinline__ int wrap20(int x) { return x >= 20 ? x - 20 : x; }
static __device__ __forceinline__ int wrap18(int x) { return x >= 18 ? x - 18 : x; }

// ---------------------------------------------------------------------------
// Fused streaming: diff -> YUV -> 2x2 pool -> 15x15 box -> square -> partial.
// Per step s (one barrier each): stage loads for pair p+1 (regs, issued early),
// hbox pair p (thread-per-col, conflict-free), vertical sliding-sum update for
// pair p-1 (6 LDS reads/col, O(1)/output), then write staged pair p+1 to LDS.
// Rolling hbox rings; all out-of-image rows/cols staged as zeros (= zero pad).
// ---------------------------------------------------------------------------
__global__ __launch_bounds__(256, 2) void fused_stream_kernel(
        const float* __restrict__ in, const float* __restrict__ tgt,
        float invY, float invC, float* __restrict__ partials) {
    __shared__ float dYs[2][2][DYW];     // [buf][row-of-pair][col]
    __shared__ float dUVs[2][2][UVW];    // [buf][plane][pooled col]
    __shared__ float hbY[NHBY][HBYW];
    __shared__ float hbU[NHBC][HBCW];
    __shared__ float hbV[NHBC][HBCW];
    __shared__ float part[4];

    const int tid = threadIdx.x;
    const int b = blockIdx.x;
    const int n     = b >> 5;
    const int band  = (b >> 2) & 7;
    const int quart = b & 3;
    const int R0 = band << 6;    // first output (full-res) row of band
    const int C0 = quart << 7;   // first output col
    const int P0 = band << 5;    // first output chroma row (= pair index)

    const size_t plane = (size_t)H * W;
    const float* pi = in  + (size_t)n * 3 * plane;
    const float* pt = tgt + (size_t)n * 3 * plane;

    // zero hbox rings (slots read before first write must return 0)
    for (int i = tid; i < NHBY * HBYW; i += 256) (&hbY[0][0])[i] = 0.f;
    for (int i = tid; i < NHBC * HBCW; i += 256) { (&hbU[0][0])[i] = 0.f; (&hbV[0][0])[i] = 0.f; }

    // roles
    const int cY  = tid & 127;          // luma col (hbox + v-upd)
    const int rp  = tid >> 7;           // luma hbox row-of-pair
    const int plc = (tid >> 6) & 1;     // chroma plane for t<128 (wave-uniform)
    const int cC  = tid & 63;           // chroma col
    float (*hbC)[HBCW] = plc ? hbV : hbU;
    const bool isStageT = tid < 40;
    const int xx = C0 - 16 + (tid << 2);          // staged full-res col (float4)
    const bool cok = (unsigned)xx < W;

    float sA = 0.f, sB = 0.f, sC = 0.f, accY = 0.f, accC = 0.f;

    // ring slots of row 2*pcur (luma) / pcur (chroma) at s = -1
    int slotW = (64 * band - 16) % 20; if (slotW < 0) slotW += 20;
    int slotC = (32 * band - 8)  % 18; if (slotC < 0) slotC += 18;

    // s = -1: stage-only prologue (pair P0-7 -> buf 0). s in [0,45]: hbox pair
    // pcur = P0-7+s. s in [1,46]: v-update pair pcur-1. Stage prefetches pcur+1.
#pragma unroll 1
    for (int s = -1; s <= 46; ++s) {
        __syncthreads();
        const int pcur = P0 - 7 + s;

        // ---- 1) issue global loads for pair pcur+1 (used at step end) ----
        const float4 z4 = make_float4(0.f, 0.f, 0.f, 0.f);
        float4 iRa=z4,iGa=z4,iBa=z4,tRa=z4,tGa=z4,tBa=z4;
        float4 iRb=z4,iGb=z4,iBb=z4,tRb=z4,tGb=z4,tBb=z4;
        const bool doStage = (s <= 44) && isStageT;
        if (doStage && cok) {
            const int pn = pcur + 1;
            const int ra = 2 * pn, rb = 2 * pn + 1;
            if ((unsigned)ra < H) {
                const size_t o = (size_t)ra * W + xx;
                iRa = *(const float4*)(pi + o);              tRa = *(const float4*)(pt + o);
                iGa = *(const float4*)(pi + plane + o);      tGa = *(const float4*)(pt + plane + o);
                iBa = *(const float4*)(pi + 2 * plane + o);  tBa = *(const float4*)(pt + 2 * plane + o);
            }
            if ((unsigned)rb < H) {
                const size_t o = (size_t)rb * W + xx;
                iRb = *(const float4*)(pi + o);              tRb = *(const float4*)(pt + o);
                iGb = *(const float4*)(pi + plane + o);      tGb = *(const float4*)(pt + plane + o);
                iBb = *(const float4*)(pi + 2 * plane + o);  tBb = *(const float4*)(pt + 2 * plane + o);
            }
        }

        // ---- 2) hbox pair pcur (reads staging buf s&1, writes rings) ----
        if (s >= 0 && s <= 45) {
            const float* rowY = dYs[s & 1][rp];
            const float t1 = (rowY[cY+1] + rowY[cY+2]) + (rowY[cY+3] + rowY[cY+4]);
            const float t2 = (rowY[cY+5] + rowY[cY+6]) + (rowY[cY+7] + rowY[cY+8]);
            const float t3 = (rowY[cY+9] + rowY[cY+10]) + (rowY[cY+11] + rowY[cY+12]);
            const float t4 = (rowY[cY+13] + rowY[cY+14]) + rowY[cY+15];
            hbY[wrap20(slotW + rp)][cY] = (t1 + t2) + (t3 + t4);
            if (tid < 128) {
                const float* rowC = dUVs[s & 1][plc];
                const float u1 = (rowC[cC+1] + rowC[cC+2]) + (rowC[cC+3] + rowC[cC+4]);
                const float u2 = (rowC[cC+5] + rowC[cC+6]) + (rowC[cC+7] + rowC[cC+8]);
                const float u3 = (rowC[cC+9] + rowC[cC+10]) + (rowC[cC+11] + rowC[cC+12]);
                const float u4 = (rowC[cC+13] + rowC[cC+14]) + rowC[cC+15];
                hbC[slotC][cC] = (u1 + u2) + (u3 + u4);
            }
        }

        // ---- 3) vertical sliding-sum update for pair pcur-1 ----
        if (s >= 1) {
            if (tid >= 128) {   // luma: out rows yA = 2*pcur-9 (odd), yB = yA+1
                const int k2 = wrap20(slotW + 2),  k3 = wrap20(slotW + 3),  k4 = wrap20(slotW + 4);
                const int k17 = wrap20(slotW + 17), k18 = wrap20(slotW + 18), k19 = wrap20(slotW + 19);
                const float h2 = hbY[k2][cY],  h3 = hbY[k3][cY],  h4 = hbY[k4][cY];
                const float h17 = hbY[k17][cY], h18 = hbY[k18][cY], h19 = hbY[k19][cY];
                sA += (h17 + h18) - (h2 + h3);
                sB += (h18 + h19) - (h3 + h4);
                const int yA = 2 * pcur - 9;
                if ((unsigned)(yA - R0) < 64u)     accY += sA * sA;
                if ((unsigned)(yA + 1 - R0) < 64u) accY += sB * sB;
            } else {            // chroma: out row kc = pcur-8
                const int kN = wrap18(slotC + 17), kO = wrap18(slotC + 2);
                sC += hbC[kN][cC] - hbC[kO][cC];
                if ((unsigned)(pcur - 8 - P0) < 32u) accC += sC * sC;
            }
        }

        // ---- 4) finish stage: diff -> Y + pooled UV -> staging buf (s+1)&1 ----
        if (doStage) {
            const float4 dRa = make_float4(iRa.x-tRa.x, iRa.y-tRa.y, iRa.z-tRa.z, iRa.w-tRa.w);
            const float4 dGa = make_float4(iGa.x-tGa.x, iGa.y-tGa.y, iGa.z-tGa.z, iGa.w-tGa.w);
            const float4 dBa = make_float4(iBa.x-tBa.x, iBa.y-tBa.y, iBa.z-tBa.z, iBa.w-tBa.w);
            const float4 dRb = make_float4(iRb.x-tRb.x, iRb.y-tRb.y, iRb.z-tRb.z, iRb.w-tRb.w);
            const float4 dGb = make_float4(iGb.x-tGb.x, iGb.y-tGb.y, iGb.z-tGb.z, iGb.w-tGb.w);
            const float4 dBb = make_float4(iBb.x-tBb.x, iBb.y-tBb.y, iBb.z-tBb.z, iBb.w-tBb.w);
            const int wb = (s + 1) & 1;
            if (tid >= 2 && tid < 38) {   // luma idx 4*tid-8 in [0,143]
                float4 ya, yb;
                ya.x = 0.299f*dRa.x + 0.587f*dGa.x + 0.114f*dBa.x;
                ya.y = 0.299f*dRa.y + 0.587f*dGa.y + 0.114f*dBa.y;
                ya.z = 0.299f*dRa.z + 0.587f*dGa.z + 0.114f*dBa.z;
                ya.w = 0.299f*dRa.w + 0.587f*dGa.w + 0.114f*dBa.w;
                yb.x = 0.299f*dRb.x + 0.587f*dGb.x + 0.114f*dBb.x;
                yb.y = 0.299f*dRb.y + 0.587f*dGb.y + 0.114f*dBb.y;
                yb.z = 0.299f*dRb.z + 0.587f*dGb.z + 0.114f*dBb.z;
                yb.w = 0.299f*dRb.w + 0.587f*dGb.w + 0.114f*dBb.w;
                *(float4*)&dYs[wb][0][4 * tid - 8] = ya;
                *(float4*)&dYs[wb][1][4 * tid - 8] = yb;
            }
            // pooled chroma (two 2x2 patches per thread; +128 cancels in diff)
            const float sr0 = (dRa.x + dRa.y) + (dRb.x + dRb.y);
            const float sg0 = (dGa.x + dGa.y) + (dGb.x + dGb.y);
            const float sb0 = (dBa.x + dBa.y) + (dBb.x + dBb.y);
            const float sr1 = (dRa.z + dRa.w) + (dRb.z + dRb.w);
            const float sg1 = (dGa.z + dGa.w) + (dGb.z + dGb.w);
            const float sb1 = (dBa.z + dBa.w) + (dBb.z + dBb.w);
            const float u0 = (-0.169f*sr0 - 0.331f*sg0 + 0.5f *sb0) * 0.25f;
            const float u1 = (-0.169f*sr1 - 0.331f*sg1 + 0.5f *sb1) * 0.25f;
            const float v0 = ( 0.5f  *sr0 - 0.46f *sg0 - 0.04f*sb0) * 0.25f;
            const float v1 = ( 0.5f  *sr1 - 0.46f *sg1 - 0.04f*sb1) * 0.25f;
            *(float2*)&dUVs[wb][0][2 * tid] = make_float2(u0, u1);
            *(float2*)&dUVs[wb][1][2 * tid] = make_float2(v0, v1);
        }

        slotW = wrap20(slotW + 2);
        slotC = wrap18(slotC + 1);
    }

    // ---- block reduction -> one partial per block ----
    float v = accY * invY + accC * invC;
    for (int o = 32; o > 0; o >>= 1) v += __shfl_down(v, o, 64);
    const int lane = tid & 63, wv = tid >> 6;
    if (lane == 0) part[wv] = v;
    __syncthreads();
    if (tid == 0)
        partials[b] = (part[0] + part[1]) + (part[2] + part[3]);
}

// ---------------------------------------------------------------------------
// Final: single-block sum of 512 partials -> out[0].
// ---------------------------------------------------------------------------
__global__ void final_reduce_kernel(const float* __restrict__ partials, int n,
                                    float* __restrict__ out) {
    float s = 0.f;
    for (int i = threadIdx.x; i < n; i += 256) s += partials[i];
    for (int o = 32; o > 0; o >>= 1) s += __shfl_down(s, o, 64);
    __shared__ float part[4];
    const int lane = threadIdx.x & 63, wid = threadIdx.x >> 6;
    if (lane == 0) part[wid] = s;
    __syncthreads();
    if (threadIdx.x == 0)
        *out = part[0] + part[1] + part[2] + part[3];
}

extern "C" void kernel_launch(void* const* d_in, const int* in_sizes, int n_in,
                              void* d_out, int out_size, void* d_ws, size_t ws_size,
                              hipStream_t stream) {
    const float* input  = (const float*)d_in[0];
    const float* target = (const float*)d_in[1];
    float* out = (float*)d_out;
    float* partials = (float*)d_ws;   // 512 floats

    const float invY = 1.0f / (float)((size_t)NIMG * H * W);            // 1/4194304
    const float invC = 1.0f / (float)((size_t)NIMG * (H/2) * (W/2));    // 1/1048576

    fused_stream_kernel<<<NIMG * 8 * 4, 256, 0, stream>>>(input, target, invY, invC, partials);
    final_reduce_kernel<<<1, 256, 0, stream>>>(partials, NIMG * 8 * 4, out);
}

// Round 5
// 144.055 us; speedup vs baseline: 1.3310x; 1.3310x over previous
//
#include <hip/hip_runtime.h>

#define NIMG 16
#define H 512
#define W 512

// 64x64 output tiles; 1024 tiles; 512 blocks x 2 tiles; 512 threads.
#define YW 84      // sY stride (floats; 80 used; 84%32=20 -> 2-way banks in phase B)
#define YR 78      // 64 + 14 halo rows
#define CW 52      // per-plane chroma stride (48 used; 52%32=20)
#define CR 46      // 32 + 14 halo pooled rows
#define NPAIR 1104 // 46 pooled rows x 24 col-quads (full-res cols C0-16 .. C0+79)

#define SUB4(d, a, b) d.x=(a).x-(b).x; d.y=(a).y-(b).y; d.z=(a).z-(b).z; d.w=(a).w-(b).w

// Raw barrier: order LDS ops, do NOT drain vmcnt -- keeps the prefetched
// global loads in flight across compute phases (__syncthreads would drain).
static __device__ __forceinline__ void barln() {
    asm volatile("s_waitcnt lgkmcnt(0)" ::: "memory");
    __builtin_amdgcn_s_barrier();
    __builtin_amdgcn_sched_barrier(0);
}

// ---------------------------------------------------------------------------
// Fused: diff -> YUV -> 2x2 pool -> 15x15 box -> square -> partial, with
// tile-level pipelining: tile t+1's global loads live in VGPRs across tile
// t's compute phases; converted + written to LDS only after tile t finishes.
// ---------------------------------------------------------------------------
__global__ __launch_bounds__(512, 2) void fused_loss_kernel(
        const float* __restrict__ in, const float* __restrict__ tgt,
        float invY, float invC, float* __restrict__ partials) {
    __shared__ float sY[YR * YW];
    __shared__ float sC[2][CR * CW];
    __shared__ float part[8];

    const int tid = threadIdx.x;
    const size_t plane = (size_t)H * W;

    float4 raw[36];          // 3 tasks x 12 float4 (r,g,b x 2 rows x in,tgt)
    float accY = 0.f, accC = 0.f;

    const int tau0 = blockIdx.x * 2;   // tiles tau0, tau0+1 (adjacent cols)

    // ---- issue raw global loads for tile tau into the register stash ----
    auto ISSUE = [&](int tau) {
        const int nim = tau >> 6;
        const int R0 = ((tau >> 3) & 7) << 6;
        const int C0 = (tau & 7) << 6;
        const float* pi = in  + (size_t)nim * 3 * plane;
        const float* pt = tgt + (size_t)nim * 3 * plane;
#pragma unroll
        for (int kk = 0; kk < 3; ++kk) {
            const int i = tid + (kk << 9);
            float4* rw = &raw[12 * kk];
            const float4 z4 = make_float4(0.f, 0.f, 0.f, 0.f);
#pragma unroll
            for (int j = 0; j < 12; ++j) rw[j] = z4;
            if (i < NPAIR) {
                const int pr = i / 24;
                const int q  = i - pr * 24;
                const int yy = R0 - 14 + 2 * pr;     // full-res row (pair top)
                const int xx = C0 - 16 + (q << 2);   // full-res col (float4)
                if ((unsigned)xx < W) {
                    if ((unsigned)yy < H) {
                        const size_t o = (size_t)yy * W + xx;
                        rw[0]  = *(const float4*)(pi + o);
                        rw[2]  = *(const float4*)(pi + plane + o);
                        rw[4]  = *(const float4*)(pi + 2 * plane + o);
                        rw[6]  = *(const float4*)(pt + o);
                        rw[8]  = *(const float4*)(pt + plane + o);
                        rw[10] = *(const float4*)(pt + 2 * plane + o);
                    }
                    if ((unsigned)(yy + 1) < H) {
                        const size_t o = (size_t)(yy + 1) * W + xx;
                        rw[1]  = *(const float4*)(pi + o);
                        rw[3]  = *(const float4*)(pi + plane + o);
                        rw[5]  = *(const float4*)(pi + 2 * plane + o);
                        rw[7]  = *(const float4*)(pt + o);
                        rw[9]  = *(const float4*)(pt + plane + o);
                        rw[11] = *(const float4*)(pt + 2 * plane + o);
                    }
                }
            }
        }
    };

    // ---- convert stash -> dY (fp32) + pooled dU/dV, write to LDS ----
    // (vmcnt waits happen here via register deps, after compute cover)
    auto CONVW = [&] {
#pragma unroll
        for (int kk = 0; kk < 3; ++kk) {
            const int i = tid + (kk << 9);
            if (i < NPAIR) {
                const int pr = i / 24;
                const int q  = i - pr * 24;
                const float4* rw = &raw[12 * kk];
                float4 dRa, dRb, dGa, dGb, dBa, dBb;
                SUB4(dRa, rw[0], rw[6]);  SUB4(dRb, rw[1], rw[7]);
                SUB4(dGa, rw[2], rw[8]);  SUB4(dGb, rw[3], rw[9]);
                SUB4(dBa, rw[4], rw[10]); SUB4(dBb, rw[5], rw[11]);

                float4 ya, yb;
                ya.x = 0.299f*dRa.x + 0.587f*dGa.x + 0.114f*dBa.x;
                ya.y = 0.299f*dRa.y + 0.587f*dGa.y + 0.114f*dBa.y;
                ya.z = 0.299f*dRa.z + 0.587f*dGa.z + 0.114f*dBa.z;
                ya.w = 0.299f*dRa.w + 0.587f*dGa.w + 0.114f*dBa.w;
                yb.x = 0.299f*dRb.x + 0.587f*dGb.x + 0.114f*dBb.x;
                yb.y = 0.299f*dRb.y + 0.587f*dGb.y + 0.114f*dBb.y;
                yb.z = 0.299f*dRb.z + 0.587f*dGb.z + 0.114f*dBb.z;
                yb.w = 0.299f*dRb.w + 0.587f*dGb.w + 0.114f*dBb.w;

                // sY col 0 <-> global col C0-8 ; sY row 0 <-> global row R0-7
                const int ly0 = 2 * pr - 7;
                const int lx  = (q << 2) - 8;
                if ((unsigned)lx < 80u) {
                    if ((unsigned)ly0 < 78u)       *(float4*)&sY[ly0 * YW + lx] = ya;
                    if ((unsigned)(ly0 + 1) < 78u) *(float4*)&sY[(ly0 + 1) * YW + lx] = yb;
                }
                // pooled chroma (two 2x2 patches; +128 cancels in diff)
                const float sr0 = (dRa.x + dRa.y) + (dRb.x + dRb.y);
                const float sg0 = (dGa.x + dGa.y) + (dGb.x + dGb.y);
                const float sb0 = (dBa.x + dBa.y) + (dBb.x + dBb.y);
                const float sr1 = (dRa.z + dRa.w) + (dRb.z + dRb.w);
                const float sg1 = (dGa.z + dGa.w) + (dGb.z + dGb.w);
                const float sb1 = (dBa.z + dBa.w) + (dBb.z + dBb.w);
                const float u0 = (-0.169f*sr0 - 0.331f*sg0 + 0.5f *sb0) * 0.25f;
                const float u1 = (-0.169f*sr1 - 0.331f*sg1 + 0.5f *sb1) * 0.25f;
                const float v0 = ( 0.5f  *sr0 - 0.46f *sg0 - 0.04f*sb0) * 0.25f;
                const float v1 = ( 0.5f  *sr1 - 0.46f *sg1 - 0.04f*sb1) * 0.25f;
                // sC col 0 <-> pooled col C0/2-8 ; row pr <-> pooled row R0/2-7+pr
                *(float2*)&sC[0][pr * CW + 2 * q] = make_float2(u0, u1);
                *(float2*)&sC[1][pr * CW + 2 * q] = make_float2(v0, v1);
            }
        }
    };

    // ---- Phase A: 15-tap hbox, in-place shifted (window [k+1,k+15] -> col k+1).
    // One thread per row: writes trail reads within the thread, race-free.
    auto PHASE_A = [&] {
        if (tid < YR) {                      // luma rows
            const int base = tid * YW;
            float s = 0.f;
#pragma unroll
            for (int j = 1; j <= 14; ++j) s += sY[base + j];
#pragma unroll
            for (int k = 0; k < 64; ++k) {
                const float vn = sY[base + 15 + k];
                const float vo = sY[base + 1 + k];
                s += vn;
                sY[base + 1 + k] = s;
                s -= vo;
            }
        } else if (tid < YR + 2 * CR) {      // chroma rows (U then V)
            const int j = tid - YR;
            float* sp = sC[j >= CR ? 1 : 0];
            const int r = (j >= CR) ? j - CR : j;
            const int base = r * CW;
            float s = 0.f;
#pragma unroll
            for (int jj = 1; jj <= 14; ++jj) s += sp[base + jj];
#pragma unroll
            for (int k = 0; k < 32; ++k) {
                const float vn = sp[base + 15 + k];
                const float vo = sp[base + 1 + k];
                s += vn;
                sp[base + 1 + k] = s;
                s -= vo;
            }
        }
    };

    // ---- Phase B: vertical 15-tap sliding sum + square (LDS reads only) ----
    auto PHASE_B = [&] {
        if (tid < 128) {                     // luma: col c, row-half hh
            const int c = tid & 63, hh = tid >> 6;
            const int y0 = hh << 5;
            float s = 0.f;
#pragma unroll
            for (int r = 0; r < 14; ++r) s += sY[(y0 + r) * YW + 1 + c];
#pragma unroll
            for (int k = 0; k < 32; ++k) {
                s += sY[(y0 + 14 + k) * YW + 1 + c];
                accY += s * s;
                s -= sY[(y0 + k) * YW + 1 + c];
            }
        } else if (tid < 256) {              // chroma: col c, plane p, half hh
            const int j = tid - 128;
            const int c = j & 31, p = (j >> 5) & 1, hh = j >> 6;
            const float* sp = sC[p];
            const int y0 = hh << 4;
            float s = 0.f;
#pragma unroll
            for (int r = 0; r < 14; ++r) s += sp[(y0 + r) * CW + 1 + c];
#pragma unroll
            for (int k = 0; k < 16; ++k) {
                s += sp[(y0 + 14 + k) * CW + 1 + c];
                accC += s * s;
                s -= sp[(y0 + k) * CW + 1 + c];
            }
        }
    };

    // ================= pipeline (manually unrolled 2 tiles) =================
    ISSUE(tau0);
    CONVW();                 // vmcnt drained by register deps here
    __syncthreads();         // safe: nothing in flight
    ISSUE(tau0 + 1);         // stash in flight across tile-0 phases

    PHASE_A();
    barln();                 // raw barrier: do NOT drain vmcnt
    PHASE_B();
    barln();                 // raw barrier: do NOT drain vmcnt
    CONVW();                 // waits tile-1 loads (covered), writes LDS
    __syncthreads();         // safe: stash consumed
    PHASE_A();
    __syncthreads();
    PHASE_B();

    // ---- block reduction -> one partial per block ----
    float v = accY * invY + accC * invC;
    for (int o = 32; o > 0; o >>= 1) v += __shfl_down(v, o, 64);
    const int lane = tid & 63, wv = tid >> 6;
    if (lane == 0) part[wv] = v;
    __syncthreads();
    if (tid == 0) {
        float s = 0.f;
#pragma unroll
        for (int j = 0; j < 8; ++j) s += part[j];
        partials[blockIdx.x] = s;
    }
}

// ---------------------------------------------------------------------------
// Final: single-block sum of 512 partials -> out[0].
// ---------------------------------------------------------------------------
__global__ void final_reduce_kernel(const float* __restrict__ partials, int n,
                                    float* __restrict__ out) {
    float s = 0.f;
    for (int i = threadIdx.x; i < n; i += 256) s += partials[i];
    for (int o = 32; o > 0; o >>= 1) s += __shfl_down(s, o, 64);
    __shared__ float part[4];
    const int lane = threadIdx.x & 63, wid = threadIdx.x >> 6;
    if (lane == 0) part[wid] = s;
    __syncthreads();
    if (threadIdx.x == 0)
        *out = part[0] + part[1] + part[2] + part[3];
}

extern "C" void kernel_launch(void* const* d_in, const int* in_sizes, int n_in,
                              void* d_out, int out_size, void* d_ws, size_t ws_size,
                              hipStream_t stream) {
    const float* input  = (const float*)d_in[0];
    const float* target = (const float*)d_in[1];
    float* out = (float*)d_out;
    float* partials = (float*)d_ws;   // 512 floats

    const float invY = 1.0f / (float)((size_t)NIMG * H * W);            // 1/4194304
    const float invC = 1.0f / (float)((size_t)NIMG * (H/2) * (W/2));    // 1/1048576

    fused_loss_kernel<<<512, 512, 0, stream>>>(input, target, invY, invC, partials);
    final_reduce_kernel<<<1, 256, 0, stream>>>(partials, 512, out);
}